// Round 4
// baseline (544.996 us; speedup 1.0000x reference)
//
#include <hip/hip_runtime.h>
#include <hip/hip_bf16.h>
#include <cstddef>
#include <cstdint>

typedef unsigned short u16;
typedef __attribute__((ext_vector_type(8))) short bf16x8;   // 8 bf16 in 4 VGPRs
typedef __attribute__((ext_vector_type(4))) float f32x4;
typedef __attribute__((ext_vector_type(8))) unsigned short u16x8;

static __device__ __forceinline__ u16 f2bf(float x) {       // RNE f32->bf16
  unsigned u = __float_as_uint(x);
  u += 0x7fffu + ((u >> 16) & 1u);
  return (u16)(u >> 16);
}
static __device__ __forceinline__ float bflo(unsigned u) { return __uint_as_float(u << 16); }
static __device__ __forceinline__ float bfhi(unsigned u) { return __uint_as_float(u & 0xffff0000u); }

// ---------------------------------------------------------------------------
// Zero the halo (row H, col W) of a padded NHWC buffer [nimg][H+1][W+1][C].
// ---------------------------------------------------------------------------
__global__ __launch_bounds__(256) void zero_halo(u16* __restrict__ buf,
                                                 int H, int W, int C, int nimg) {
  const int c8n = C >> 3;
  const long long total = (long long)nimg * (W + 1 + H) * c8n;
  const long long i = (long long)blockIdx.x * 256 + threadIdx.x;
  if (i >= total) return;
  const int c8 = (int)(i % c8n);
  long long rem = i / c8n;
  const int p = (int)(rem % (W + 1 + H));
  const int n = (int)(rem / (W + 1 + H));
  int y, x;
  if (p <= W) { y = H; x = p; } else { y = p - (W + 1); x = W; }
  const u16x8 z = {0, 0, 0, 0, 0, 0, 0, 0};
  *(u16x8*)(buf + (((size_t)n * (H + 1) + y) * (W + 1) + x) * C + c8 * 8) = z;
}

// ---------------------------------------------------------------------------
// conv1: 3->64ch, 3x3 s2 SAME, fp32 NCHW in -> bf16 padded-NHWC out.
// ---------------------------------------------------------------------------
__global__ __launch_bounds__(256) void conv1_s2(
    const float* __restrict__ in,   // [n][3][224][224]
    const float* __restrict__ w,    // [64][3][3][3] OIHW
    const float* __restrict__ bias,
    u16* __restrict__ out) {        // [n][113][113][64] (halo untouched)
  __shared__ float sw[64 * 27];
  __shared__ float sb[64];
  const int tid = threadIdx.x;
  if (tid < 64) sb[tid] = bias[tid];
  for (int i = tid; i < 64 * 27; i += 256) sw[i] = w[i];
  __syncthreads();
  const int n = blockIdx.y;
  const int by = blockIdx.x / 7, bx = blockIdx.x % 7;
  const int oy = by * 16 + (tid >> 4), ox = bx * 16 + (tid & 15);
  const float* ibase = in + (size_t)n * 3 * 224 * 224 + (size_t)(2 * oy) * 224 + 2 * ox;
  float v[27];
  #pragma unroll
  for (int c = 0; c < 3; ++c)
    #pragma unroll
    for (int r = 0; r < 3; ++r)
      #pragma unroll
      for (int s = 0; s < 3; ++s) {
        const int iy = 2 * oy + r, ix = 2 * ox + s;
        float x = 0.f;
        if (iy < 224 && ix < 224) x = ibase[(size_t)c * 224 * 224 + r * 224 + s];
        v[c * 9 + r * 3 + s] = x;
      }
  u16* obase = out + (((size_t)n * 113 + oy) * 113 + ox) * 64;
  #pragma unroll
  for (int kc = 0; kc < 8; ++kc) {
    u16x8 pack;
    #pragma unroll
    for (int k8 = 0; k8 < 8; ++k8) {
      const int k = kc * 8 + k8;
      float a = sb[k];
      const float* wk = &sw[k * 27];
      #pragma unroll
      for (int t = 0; t < 27; ++t) a = fmaf(v[t], wk[t], a);
      pack[k8] = f2bf(fmaxf(a, 0.f));
    }
    *(u16x8*)(obase + kc * 8) = pack;
  }
}

// ---------------------------------------------------------------------------
// Weight repack: OIHW fp32 [K][C][3][3] -> MFMA-fragment-ordered bf16.
// ---------------------------------------------------------------------------
template<int C, int K>
__global__ __launch_bounds__(256) void pack_w(const float* __restrict__ w,
                                              u16* __restrict__ pw) {
  constexpr int CB = C / 32, NB = K / 16;
  const int idx = blockIdx.x * 256 + threadIdx.x;
  if (idx >= 9 * C * K) return;
  const int j = idx & 7;
  const int L = (idx >> 3) & 63;
  int t = idx >> 9;
  const int nbg = t % NB; t /= NB;
  const int cb = t % CB;
  const int tap = t / CB;
  const int n = nbg * 16 + (L & 15);
  const int c = cb * 32 + ((L >> 4) << 3) + j;
  pw[idx] = f2bf(w[((size_t)n * C + c) * 9 + tap]);
}

// ---------------------------------------------------------------------------
// Implicit-GEMM 3x3 s2 conv, padded NHWC bf16, fp32 accum, bias+ReLU.
// Block 256 = 4 waves (2m x 2n); block tile 128px x 128outch; wave 64px x 64ch
// = 4x4 frags. EXPLICIT register double-buffer, prefetch distance 2: two named
// a/b register sets rotated with static indices; step t+2's loads issue right
// after step t's MFMAs so ~2 steps of MFMA issue cover the L2-hit latency.
// ---------------------------------------------------------------------------
template<int C, int K, int OH, int OW>
__global__ __launch_bounds__(256) void conv3x3s2_mfma(
    const u16* __restrict__ in,   // [n][2OH+1][2OW+1][C] padded
    const u16* __restrict__ pw,   // packed fragment weights
    const float* __restrict__ bias,
    u16* __restrict__ out) {      // [n][OH+1][OW+1][K] padded
  constexpr int IH = 2 * OH, IW = 2 * OW;
  constexpr int PIW = IW + 1;
  constexpr int P = OH * OW;
  constexpr int BM = 128;
  constexpr int MB = (P + BM - 1) / BM;
  constexpr int CB = C / 32, NB = K / 16;
  constexpr int STEPS = 9 * CB;               // even for all convs here
  const int bm = blockIdx.x % MB;
  const int n = blockIdx.x / MB;
  const int nbh = blockIdx.y;
  const int lane = threadIdx.x & 63, wv = threadIdx.x >> 6;
  const int mh = wv >> 1, nh = wv & 1;
  const int nbase = nbh * 8 + nh * 4;
  const int kg = (lane >> 4) << 3;

  const u16* ibase = in + (size_t)n * ((IH + 1) * PIW * C);
  const u16* bbase = pw + (size_t)nbase * 512 + lane * 8;
  int abase[4];
  #pragma unroll
  for (int mf = 0; mf < 4; ++mf) {
    int pm = bm * BM + mh * 64 + mf * 16 + (lane & 15);
    int pc = pm < P ? pm : P - 1;             // clamp: dup loads, guarded store
    int oy = pc / OW, ox = pc % OW;
    abase[mf] = ((2 * oy) * PIW + 2 * ox) * C + kg;
  }

  f32x4 acc[4][4];
  #pragma unroll
  for (int mf = 0; mf < 4; ++mf)
    #pragma unroll
    for (int nf = 0; nf < 4; ++nf) acc[mf][nf] = (f32x4){0.f, 0.f, 0.f, 0.f};

  bf16x8 a0[4], b0[4], a1[4], b1[4];

  auto LOAD = [&](int st, bf16x8* a, bf16x8* b) {
    const int tap = st / CB, cb = st % CB;    // compile-time after unroll
    const int r = tap / 3, s = tap - 3 * r;
    const int toff = (r * PIW + s) * C + cb * 32;
    #pragma unroll
    for (int mf = 0; mf < 4; ++mf)
      a[mf] = *(const bf16x8*)(ibase + abase[mf] + toff);
    const u16* bp = bbase + (size_t)st * (NB * 512);
    #pragma unroll
    for (int nf = 0; nf < 4; ++nf) b[nf] = *(const bf16x8*)(bp + nf * 512);
  };
  auto MFMA_STEP = [&](bf16x8* a, bf16x8* b) {
    #pragma unroll
    for (int mf = 0; mf < 4; ++mf)
      #pragma unroll
      for (int nf = 0; nf < 4; ++nf)
        acc[mf][nf] = __builtin_amdgcn_mfma_f32_16x16x32_bf16(a[mf], b[nf], acc[mf][nf], 0, 0, 0);
  };

  LOAD(0, a0, b0);
  LOAD(1, a1, b1);
  #pragma unroll
  for (int st = 0; st < STEPS; st += 2) {
    MFMA_STEP(a0, b0);
    if (st + 2 < STEPS) LOAD(st + 2, a0, b0);
    MFMA_STEP(a1, b1);
    if (st + 3 < STEPS) LOAD(st + 3, a1, b1);
  }

  // Epilogue: D col=lane&15 (outch), row=(lane>>4)*4+reg (pixel)
  const int rowg = (lane >> 4) << 2;
  #pragma unroll
  for (int mf = 0; mf < 4; ++mf)
    #pragma unroll
    for (int nf = 0; nf < 4; ++nf) {
      const int ch = (nbase + nf) * 16 + (lane & 15);
      const float bv = bias[ch];
      #pragma unroll
      for (int rr = 0; rr < 4; ++rr) {
        const int pix = bm * BM + mh * 64 + mf * 16 + rowg + rr;
        if (pix < P) {
          const int oy = pix / OW, ox = pix % OW;
          out[(((size_t)n * (OH + 1) + oy) * (OW + 1) + ox) * K + ch] =
              f2bf(fmaxf(acc[mf][nf][rr] + bv, 0.f));
        }
      }
    }
}

// ---------------------------------------------------------------------------
// Global avg pool over 14x14 of padded [nb][15][15][512] bf16 -> feats fp32.
// ---------------------------------------------------------------------------
__global__ __launch_bounds__(256) void avgpool_nhwc(
    const u16* __restrict__ in, float* __restrict__ feats, int n0) {
  const int n = blockIdx.x, t = threadIdx.x;
  const u16* p = in + (size_t)n * (15 * 15 * 512) + t * 2;
  float s0 = 0.f, s1 = 0.f;
  for (int y = 0; y < 14; ++y)
    #pragma unroll
    for (int x = 0; x < 14; ++x) {
      unsigned u = *(const unsigned*)(p + (size_t)(y * 15 + x) * 512);
      s0 += bflo(u);
      s1 += bfhi(u);
    }
  float* f = feats + (size_t)(n0 + n) * 1024;
  f[2 * t] = s0 * (1.f / 196.f);
  f[2 * t + 1] = s1 * (1.f / 196.f);
}

// ---------------------------------------------------------------------------
// Text branch: masked mean of embedding rows. One block per batch row.
// ---------------------------------------------------------------------------
__global__ __launch_bounds__(256) void embed_mean_kernel(
    const int* __restrict__ seq, const int* __restrict__ len,
    const float* __restrict__ emb, float* __restrict__ means) {
  const int b = blockIdx.x;
  const int L = len[b];
  const int d = threadIdx.x;
  float a0 = 0.f, a1 = 0.f;
  for (int s = 0; s < L; ++s) {
    const float* e = emb + (size_t)seq[b * 128 + s] * 512;
    a0 += e[d];
    a1 += e[d + 256];
  }
  const float inv = 1.f / (float)L;
  means[b * 512 + d] = a0 * inv;
  means[b * 512 + d + 256] = a1 * inv;
}

// ---------------------------------------------------------------------------
// Small FC (fp32): out[m][col] = act(x[m] . W[:,col] + b[col]), W [K][N].
// ---------------------------------------------------------------------------
template<int K, int N, bool RELU>
__global__ __launch_bounds__(256) void fc_kernel(
    const float* __restrict__ x, int ldx,
    const float* __restrict__ w, const float* __restrict__ bias,
    float* __restrict__ out, int ldo) {
  __shared__ float row[K];
  const int m = blockIdx.y;
  for (int i = threadIdx.x; i < K; i += 256) row[i] = x[(size_t)m * ldx + i];
  __syncthreads();
  const int col = blockIdx.x * 256 + threadIdx.x;
  if (col < N) {
    float a = bias[col];
    for (int k = 0; k < K; ++k) a = fmaf(row[k], w[(size_t)k * N + col], a);
    out[(size_t)m * ldo + col] = RELU ? fmaxf(a, 0.f) : a;
  }
}

// ---------------------------------------------------------------------------
extern "C" void kernel_launch(void* const* d_in, const int* in_sizes, int n_in,
                              void* d_out, int out_size, void* d_ws, size_t ws_size,
                              hipStream_t stream) {
  const float* images = (const float*)d_in[0];
  const int*   seq    = (const int*)d_in[1];
  const int*   len    = (const int*)d_in[2];
  const float* emb    = (const float*)d_in[4];
  const float* cw1 = (const float*)d_in[5];  const float* cb1 = (const float*)d_in[6];
  const float* cw2 = (const float*)d_in[7];  const float* cb2 = (const float*)d_in[8];
  const float* cw3 = (const float*)d_in[9];  const float* cb3 = (const float*)d_in[10];
  const float* cw4 = (const float*)d_in[11]; const float* cb4 = (const float*)d_in[12];
  const float* rnn_w = (const float*)d_in[13]; const float* rnn_b = (const float*)d_in[14];
  const float* fc1_w = (const float*)d_in[15]; const float* fc1_b = (const float*)d_in[16];
  const float* fc2_w = (const float*)d_in[17]; const float* fc2_b = (const float*)d_in[18];
  const float* clf_w = (const float*)d_in[19]; const float* clf_b = (const float*)d_in[20];
  float* out = (float*)d_out;

  // Padded NHWC buffers (elems/img)
  const size_t A_E = (size_t)113 * 113 * 64;   // conv1 out
  const size_t B_E = (size_t)57 * 57 * 128;    // conv2 out
  const size_t C_E = (size_t)29 * 29 * 256;    // conv3 out
  const size_t D_E = (size_t)15 * 15 * 512;    // conv4 out
  const size_t PW2_E = 9 * 64 * 128, PW3_E = 9 * 128 * 256, PW4_E = 9 * 256 * 512;
  const size_t PER_IMG = (A_E + B_E + C_E + D_E) * 2;
  const size_t FIXED = (PW2_E + PW3_E + PW4_E) * 2 +
                       (size_t)(64 * 512 + 64 * 1024 + 64 * 512 + 64 * 512) * 4;
  int chunk = 64;
  if (ws_size < FIXED + 64 * PER_IMG) {
    size_t avail = (ws_size > FIXED) ? (ws_size - FIXED) : 0;
    size_t c = avail / PER_IMG;
    chunk = (c < 1) ? 1 : (c > 64 ? 64 : (int)c);
  }
  u16* bufA = (u16*)d_ws;
  u16* bufB = bufA + (size_t)chunk * A_E;
  u16* bufC = bufB + (size_t)chunk * B_E;
  u16* bufD = bufC + (size_t)chunk * C_E;
  u16* pw2 = bufD + (size_t)chunk * D_E;
  u16* pw3 = pw2 + PW2_E;
  u16* pw4 = pw3 + PW3_E;
  float* means = (float*)(pw4 + PW4_E);
  float* feats = means + 64 * 512;
  float* h1 = feats + 64 * 1024;
  float* h2 = h1 + 64 * 512;

  // weight repack (tiny)
  pack_w<64, 128><<<(9 * 64 * 128 + 255) / 256, 256, 0, stream>>>(cw2, pw2);
  pack_w<128, 256><<<(9 * 128 * 256 + 255) / 256, 256, 0, stream>>>(cw3, pw3);
  pack_w<256, 512><<<(9 * 256 * 512 + 255) / 256, 256, 0, stream>>>(cw4, pw4);

  // zero halos once per launch
  {
    long long t1 = (long long)chunk * (113 + 112) * (64 / 8);
    long long t2 = (long long)chunk * (57 + 56) * (128 / 8);
    long long t3 = (long long)chunk * (29 + 28) * (256 / 8);
    zero_halo<<<(int)((t1 + 255) / 256), 256, 0, stream>>>(bufA, 112, 112, 64, chunk);
    zero_halo<<<(int)((t2 + 255) / 256), 256, 0, stream>>>(bufB, 56, 56, 128, chunk);
    zero_halo<<<(int)((t3 + 255) / 256), 256, 0, stream>>>(bufC, 28, 28, 256, chunk);
  }

  // text branch
  embed_mean_kernel<<<64, 256, 0, stream>>>(seq, len, emb, means);
  fc_kernel<512, 512, false><<<dim3(2, 64), 256, 0, stream>>>(
      means, 512, rnn_w, rnn_b, feats + 512, 1024);

  // image branch
  for (int n0 = 0; n0 < 64; n0 += chunk) {
    int nb = 64 - n0; if (nb > chunk) nb = chunk;
    conv1_s2<<<dim3(49, nb), 256, 0, stream>>>(
        images + (size_t)n0 * 3 * 224 * 224, cw1, cb1, bufA);
    conv3x3s2_mfma<64, 128, 56, 56><<<dim3(25 * nb, 1), 256, 0, stream>>>(
        bufA, pw2, cb2, bufB);
    conv3x3s2_mfma<128, 256, 28, 28><<<dim3(7 * nb, 2), 256, 0, stream>>>(
        bufB, pw3, cb3, bufC);
    conv3x3s2_mfma<256, 512, 14, 14><<<dim3(2 * nb, 4), 256, 0, stream>>>(
        bufC, pw4, cb4, bufD);
    avgpool_nhwc<<<nb, 256, 0, stream>>>(bufD, feats, n0);
  }

  // head
  fc_kernel<1024, 512, true ><<<dim3(2, 64), 256, 0, stream>>>(feats, 1024, fc1_w, fc1_b, h1, 512);
  fc_kernel<512,  512, true ><<<dim3(2, 64), 256, 0, stream>>>(h1,    512,  fc2_w, fc2_b, h2, 512);
  fc_kernel<512, 1000, false><<<dim3(4, 64), 256, 0, stream>>>(h2,    512,  clf_w, clf_b, out, 1000);
}

// Round 5
// 429.433 us; speedup vs baseline: 1.2691x; 1.2691x over previous
//
#include <hip/hip_runtime.h>
#include <hip/hip_bf16.h>
#include <cstddef>
#include <cstdint>

typedef unsigned short u16;
typedef __attribute__((ext_vector_type(8))) short bf16x8;   // 8 bf16 in 4 VGPRs
typedef __attribute__((ext_vector_type(4))) float f32x4;
typedef __attribute__((ext_vector_type(8))) unsigned short u16x8;

static __device__ __forceinline__ u16 f2bf(float x) {       // RNE f32->bf16
  unsigned u = __float_as_uint(x);
  u += 0x7fffu + ((u >> 16) & 1u);
  return (u16)(u >> 16);
}
static __device__ __forceinline__ float bflo(unsigned u) { return __uint_as_float(u << 16); }
static __device__ __forceinline__ float bfhi(unsigned u) { return __uint_as_float(u & 0xffff0000u); }

// async global->LDS, 16B/lane; LDS dest = wave-uniform base + lane*16 (m104)
static __device__ __forceinline__ void gll16(const u16* g, u16* l) {
  __builtin_amdgcn_global_load_lds(
      (const __attribute__((address_space(1))) void*)g,
      (__attribute__((address_space(3))) void*)l, 16, 0, 0);
}

// ---------------------------------------------------------------------------
// Zero the halo (row H, col W) of a padded NHWC buffer [nimg][H+1][W+1][C].
// ---------------------------------------------------------------------------
__global__ __launch_bounds__(256) void zero_halo(u16* __restrict__ buf,
                                                 int H, int W, int C, int nimg) {
  const int c8n = C >> 3;
  const long long total = (long long)nimg * (W + 1 + H) * c8n;
  const long long i = (long long)blockIdx.x * 256 + threadIdx.x;
  if (i >= total) return;
  const int c8 = (int)(i % c8n);
  long long rem = i / c8n;
  const int p = (int)(rem % (W + 1 + H));
  const int n = (int)(rem / (W + 1 + H));
  int y, x;
  if (p <= W) { y = H; x = p; } else { y = p - (W + 1); x = W; }
  const u16x8 z = {0, 0, 0, 0, 0, 0, 0, 0};
  *(u16x8*)(buf + (((size_t)n * (H + 1) + y) * (W + 1) + x) * C + c8 * 8) = z;
}

// ---------------------------------------------------------------------------
// conv1: 3->64ch, 3x3 s2 SAME, fp32 NCHW in -> bf16 padded-NHWC out.
// ---------------------------------------------------------------------------
__global__ __launch_bounds__(256) void conv1_s2(
    const float* __restrict__ in,   // [n][3][224][224]
    const float* __restrict__ w,    // [64][3][3][3] OIHW
    const float* __restrict__ bias,
    u16* __restrict__ out) {        // [n][113][113][64] (halo untouched)
  __shared__ float sw[64 * 27];
  __shared__ float sb[64];
  const int tid = threadIdx.x;
  if (tid < 64) sb[tid] = bias[tid];
  for (int i = tid; i < 64 * 27; i += 256) sw[i] = w[i];
  __syncthreads();
  const int n = blockIdx.y;
  const int by = blockIdx.x / 7, bx = blockIdx.x % 7;
  const int oy = by * 16 + (tid >> 4), ox = bx * 16 + (tid & 15);
  const float* ibase = in + (size_t)n * 3 * 224 * 224 + (size_t)(2 * oy) * 224 + 2 * ox;
  float v[27];
  #pragma unroll
  for (int c = 0; c < 3; ++c)
    #pragma unroll
    for (int r = 0; r < 3; ++r)
      #pragma unroll
      for (int s = 0; s < 3; ++s) {
        const int iy = 2 * oy + r, ix = 2 * ox + s;
        float x = 0.f;
        if (iy < 224 && ix < 224) x = ibase[(size_t)c * 224 * 224 + r * 224 + s];
        v[c * 9 + r * 3 + s] = x;
      }
  u16* obase = out + (((size_t)n * 113 + oy) * 113 + ox) * 64;
  #pragma unroll
  for (int kc = 0; kc < 8; ++kc) {
    u16x8 pack;
    #pragma unroll
    for (int k8 = 0; k8 < 8; ++k8) {
      const int k = kc * 8 + k8;
      float a = sb[k];
      const float* wk = &sw[k * 27];
      #pragma unroll
      for (int t = 0; t < 27; ++t) a = fmaf(v[t], wk[t], a);
      pack[k8] = f2bf(fmaxf(a, 0.f));
    }
    *(u16x8*)(obase + kc * 8) = pack;
  }
}

// ---------------------------------------------------------------------------
// Weight repack: OIHW fp32 [K][C][3][3] -> MFMA-fragment-ordered bf16.
// pw[((st)*NB + nfrag)*512 + lane*8 + j], st = tap*CB+cb
// ---------------------------------------------------------------------------
template<int C, int K>
__global__ __launch_bounds__(256) void pack_w(const float* __restrict__ w,
                                              u16* __restrict__ pw) {
  constexpr int CB = C / 32, NB = K / 16;
  const int idx = blockIdx.x * 256 + threadIdx.x;
  if (idx >= 9 * C * K) return;
  const int j = idx & 7;
  const int L = (idx >> 3) & 63;
  int t = idx >> 9;
  const int nbg = t % NB; t /= NB;
  const int cb = t % CB;
  const int tap = t / CB;
  const int n = nbg * 16 + (L & 15);
  const int c = cb * 32 + ((L >> 4) << 3) + j;
  pw[idx] = f2bf(w[((size_t)n * C + c) * 9 + tap]);
}

// ---------------------------------------------------------------------------
// Implicit-GEMM 3x3 s2 conv, m97-style LDS pipeline.
// Block 256 = 4 waves (2mh x 2nh); block tile 128px x 128outch; wave 64x64
// = 4x4 frags. Per K-step (tap,cb): stage NEXT step's fragments into buf^1
// via global_load_lds (im2col via per-lane global src addr; LDS dest linear,
// fragment-ordered), ds_read_b128 current buf, 16 MFMA, one barrier.
// Roles: wv0/wv2 stage A (mh=0/1), wv1/wv3 stage B (frags 0-3/4-7).
// ---------------------------------------------------------------------------
template<int C, int K, int OH, int OW>
__global__ __launch_bounds__(256) void conv3x3s2_mfma(
    const u16* __restrict__ in,   // [n][2OH+1][2OW+1][C] padded
    const u16* __restrict__ pw,   // packed fragment weights
    const float* __restrict__ bias,
    u16* __restrict__ out) {      // [n][OH+1][OW+1][K] padded
  constexpr int IH = 2 * OH, IW = 2 * OW;
  constexpr int PIW = IW + 1;
  constexpr int P = OH * OW;
  constexpr int BM = 128;
  constexpr int MB = (P + BM - 1) / BM;
  constexpr int CB = C / 32, NB = K / 16;
  constexpr int STEPS = 9 * CB;

  __shared__ u16 lds[2][8192];                // 2 x 16KB: A frags [0..4095], B [4096..8191]

  const int bm = blockIdx.x % MB;
  const int n = blockIdx.x / MB;
  const int nbh = blockIdx.y;                 // 128-outch group
  const int lane = threadIdx.x & 63, wv = threadIdx.x >> 6;
  const int mh = wv >> 1, nh = wv & 1;

  const u16* ibase = in + (size_t)n * ((IH + 1) * PIW * C);
  // staging source offsets for A-stager waves (nh==0): lane L holds the
  // fragment element (px = base + L%16, ch = (L/16)*8) -> im2col addr.
  int s_abase[4];
  #pragma unroll
  for (int mf = 0; mf < 4; ++mf) {
    int pm = bm * BM + mh * 64 + mf * 16 + (lane & 15);
    int pc = pm < P ? pm : P - 1;             // clamp: dup loads, guarded store
    int oy = pc / OW, ox = pc % OW;
    s_abase[mf] = ((2 * oy) * PIW + 2 * ox) * C + ((lane >> 4) << 3);
  }

  f32x4 acc[4][4];
  #pragma unroll
  for (int mf = 0; mf < 4; ++mf)
    #pragma unroll
    for (int nf = 0; nf < 4; ++nf) acc[mf][nf] = (f32x4){0.f, 0.f, 0.f, 0.f};

  auto STAGE = [&](int st, int buf) {
    if (nh == 0) {                            // wv0/wv2: A for own mh
      const int cb = st & (CB - 1);
      const int tap = st / CB;                // CB is power of 2
      const int r = tap / 3, s = tap - 3 * r;
      const int toff = (r * PIW + s) * C + cb * 32;
      #pragma unroll
      for (int mf = 0; mf < 4; ++mf)
        gll16(ibase + s_abase[mf] + toff, &lds[buf][(mh * 4 + mf) * 512]);
    } else {                                  // wv1/wv3: B frags mh*4..mh*4+3
      const u16* bp = pw + ((size_t)st * NB + nbh * 8 + mh * 4) * 512 + lane * 8;
      #pragma unroll
      for (int nf = 0; nf < 4; ++nf)
        gll16(bp + nf * 512, &lds[buf][4096 + (mh * 4 + nf) * 512]);
    }
  };

  STAGE(0, 0);
  __syncthreads();
  for (int st = 0; st < STEPS; ++st) {
    const int buf = st & 1;
    if (st + 1 < STEPS) STAGE(st + 1, buf ^ 1);
    bf16x8 a[4], b[4];
    #pragma unroll
    for (int mf = 0; mf < 4; ++mf)
      a[mf] = *(const bf16x8*)&lds[buf][(mh * 4 + mf) * 512 + lane * 8];
    #pragma unroll
    for (int nf = 0; nf < 4; ++nf)
      b[nf] = *(const bf16x8*)&lds[buf][4096 + (nh * 4 + nf) * 512 + lane * 8];
    #pragma unroll
    for (int mf = 0; mf < 4; ++mf)
      #pragma unroll
      for (int nf = 0; nf < 4; ++nf)
        acc[mf][nf] = __builtin_amdgcn_mfma_f32_16x16x32_bf16(a[mf], b[nf], acc[mf][nf], 0, 0, 0);
    __syncthreads();
  }

  // Epilogue: D col=lane&15 (outch), row=(lane>>4)*4+reg (pixel)
  const int rowg = (lane >> 4) << 2;
  #pragma unroll
  for (int mf = 0; mf < 4; ++mf)
    #pragma unroll
    for (int nf = 0; nf < 4; ++nf) {
      const int ch = (nbh * 8 + nh * 4 + nf) * 16 + (lane & 15);
      const float bv = bias[ch];
      #pragma unroll
      for (int rr = 0; rr < 4; ++rr) {
        const int pix = bm * BM + mh * 64 + mf * 16 + rowg + rr;
        if (pix < P) {
          const int oy = pix / OW, ox = pix % OW;
          out[(((size_t)n * (OH + 1) + oy) * (OW + 1) + ox) * K + ch] =
              f2bf(fmaxf(acc[mf][nf][rr] + bv, 0.f));
        }
      }
    }
}

// ---------------------------------------------------------------------------
// Global avg pool over 14x14 of padded [nb][15][15][512] bf16 -> feats fp32.
// ---------------------------------------------------------------------------
__global__ __launch_bounds__(256) void avgpool_nhwc(
    const u16* __restrict__ in, float* __restrict__ feats, int n0) {
  const int n = blockIdx.x, t = threadIdx.x;
  const u16* p = in + (size_t)n * (15 * 15 * 512) + t * 2;
  float s0 = 0.f, s1 = 0.f;
  for (int y = 0; y < 14; ++y)
    #pragma unroll
    for (int x = 0; x < 14; ++x) {
      unsigned u = *(const unsigned*)(p + (size_t)(y * 15 + x) * 512);
      s0 += bflo(u);
      s1 += bfhi(u);
    }
  float* f = feats + (size_t)(n0 + n) * 1024;
  f[2 * t] = s0 * (1.f / 196.f);
  f[2 * t + 1] = s1 * (1.f / 196.f);
}

// ---------------------------------------------------------------------------
// Text branch: masked mean, 4 parallel s-chains (ILP) x 64 lanes x 8 dims.
// ---------------------------------------------------------------------------
__global__ __launch_bounds__(256) void embed_mean_kernel(
    const int* __restrict__ seq, const int* __restrict__ len,
    const float* __restrict__ emb, float* __restrict__ means) {
  __shared__ float part[3][512];
  const int b = blockIdx.x;
  const int L = len[b];
  const int sg = threadIdx.x >> 6;            // 0..3 s-chain
  const int d0 = (threadIdx.x & 63) * 8;      // 8 dims per lane
  float a[8] = {0.f, 0.f, 0.f, 0.f, 0.f, 0.f, 0.f, 0.f};
  for (int s = sg; s < L; s += 4) {
    const float* e = emb + (size_t)seq[b * 128 + s] * 512 + d0;
    float4 v0 = *(const float4*)e, v1 = *(const float4*)(e + 4);
    a[0] += v0.x; a[1] += v0.y; a[2] += v0.z; a[3] += v0.w;
    a[4] += v1.x; a[5] += v1.y; a[6] += v1.z; a[7] += v1.w;
  }
  if (sg) {
    #pragma unroll
    for (int j = 0; j < 8; ++j) part[sg - 1][d0 + j] = a[j];
  }
  __syncthreads();
  if (sg == 0) {
    const float inv = 1.f / (float)L;
    #pragma unroll
    for (int j = 0; j < 8; ++j)
      means[(size_t)b * 512 + d0 + j] =
          (a[j] + part[0][d0 + j] + part[1][d0 + j] + part[2][d0 + j]) * inv;
  }
}

// ---------------------------------------------------------------------------
// Small FC (fp32): 2 m-rows per block, 4-way k-ILP. W row-major [K][N].
// ---------------------------------------------------------------------------
template<int K, int N, bool RELU>
__global__ __launch_bounds__(256) void fc_kernel(
    const float* __restrict__ x, int ldx,
    const float* __restrict__ w, const float* __restrict__ bias,
    float* __restrict__ out, int ldo) {
  __shared__ float row[2][K];
  const int m0 = blockIdx.y * 2;
  for (int i = threadIdx.x; i < 2 * K; i += 256)
    row[i / K][i % K] = x[(size_t)(m0 + i / K) * ldx + (i % K)];
  __syncthreads();
  const int col = blockIdx.x * 256 + threadIdx.x;
  if (col < N) {
    float acc[2][4] = {{0.f, 0.f, 0.f, 0.f}, {0.f, 0.f, 0.f, 0.f}};
    for (int k = 0; k < K; k += 4) {
      float w0 = w[(size_t)(k + 0) * N + col];
      float w1 = w[(size_t)(k + 1) * N + col];
      float w2 = w[(size_t)(k + 2) * N + col];
      float w3 = w[(size_t)(k + 3) * N + col];
      #pragma unroll
      for (int m = 0; m < 2; ++m) {
        acc[m][0] = fmaf(row[m][k + 0], w0, acc[m][0]);
        acc[m][1] = fmaf(row[m][k + 1], w1, acc[m][1]);
        acc[m][2] = fmaf(row[m][k + 2], w2, acc[m][2]);
        acc[m][3] = fmaf(row[m][k + 3], w3, acc[m][3]);
      }
    }
    const float bv = bias[col];
    #pragma unroll
    for (int m = 0; m < 2; ++m) {
      float a = acc[m][0] + acc[m][1] + acc[m][2] + acc[m][3] + bv;
      out[(size_t)(m0 + m) * ldo + col] = RELU ? fmaxf(a, 0.f) : a;
    }
  }
}

// ---------------------------------------------------------------------------
extern "C" void kernel_launch(void* const* d_in, const int* in_sizes, int n_in,
                              void* d_out, int out_size, void* d_ws, size_t ws_size,
                              hipStream_t stream) {
  const float* images = (const float*)d_in[0];
  const int*   seq    = (const int*)d_in[1];
  const int*   len    = (const int*)d_in[2];
  const float* emb    = (const float*)d_in[4];
  const float* cw1 = (const float*)d_in[5];  const float* cb1 = (const float*)d_in[6];
  const float* cw2 = (const float*)d_in[7];  const float* cb2 = (const float*)d_in[8];
  const float* cw3 = (const float*)d_in[9];  const float* cb3 = (const float*)d_in[10];
  const float* cw4 = (const float*)d_in[11]; const float* cb4 = (const float*)d_in[12];
  const float* rnn_w = (const float*)d_in[13]; const float* rnn_b = (const float*)d_in[14];
  const float* fc1_w = (const float*)d_in[15]; const float* fc1_b = (const float*)d_in[16];
  const float* fc2_w = (const float*)d_in[17]; const float* fc2_b = (const float*)d_in[18];
  const float* clf_w = (const float*)d_in[19]; const float* clf_b = (const float*)d_in[20];
  float* out = (float*)d_out;

  // Padded NHWC buffers (elems/img)
  const size_t A_E = (size_t)113 * 113 * 64;   // conv1 out
  const size_t B_E = (size_t)57 * 57 * 128;    // conv2 out
  const size_t C_E = (size_t)29 * 29 * 256;    // conv3 out
  const size_t D_E = (size_t)15 * 15 * 512;    // conv4 out
  const size_t PW2_E = 9 * 64 * 128, PW3_E = 9 * 128 * 256, PW4_E = 9 * 256 * 512;
  const size_t PER_IMG = (A_E + B_E + C_E + D_E) * 2;
  const size_t FIXED = (PW2_E + PW3_E + PW4_E) * 2 +
                       (size_t)(64 * 512 + 64 * 1024 + 64 * 512 + 64 * 512) * 4;
  int chunk = 64;
  if (ws_size < FIXED + 64 * PER_IMG) {
    size_t avail = (ws_size > FIXED) ? (ws_size - FIXED) : 0;
    size_t c = avail / PER_IMG;
    chunk = (c < 1) ? 1 : (c > 64 ? 64 : (int)c);
  }
  u16* bufA = (u16*)d_ws;
  u16* bufB = bufA + (size_t)chunk * A_E;
  u16* bufC = bufB + (size_t)chunk * B_E;
  u16* bufD = bufC + (size_t)chunk * C_E;
  u16* pw2 = bufD + (size_t)chunk * D_E;
  u16* pw3 = pw2 + PW2_E;
  u16* pw4 = pw3 + PW3_E;
  float* means = (float*)(pw4 + PW4_E);
  float* feats = means + 64 * 512;
  float* h1 = feats + 64 * 1024;
  float* h2 = h1 + 64 * 512;

  // weight repack (tiny)
  pack_w<64, 128><<<(9 * 64 * 128 + 255) / 256, 256, 0, stream>>>(cw2, pw2);
  pack_w<128, 256><<<(9 * 128 * 256 + 255) / 256, 256, 0, stream>>>(cw3, pw3);
  pack_w<256, 512><<<(9 * 256 * 512 + 255) / 256, 256, 0, stream>>>(cw4, pw4);

  // zero halos once per launch
  {
    long long t1 = (long long)chunk * (113 + 112) * (64 / 8);
    long long t2 = (long long)chunk * (57 + 56) * (128 / 8);
    long long t3 = (long long)chunk * (29 + 28) * (256 / 8);
    zero_halo<<<(int)((t1 + 255) / 256), 256, 0, stream>>>(bufA, 112, 112, 64, chunk);
    zero_halo<<<(int)((t2 + 255) / 256), 256, 0, stream>>>(bufB, 56, 56, 128, chunk);
    zero_halo<<<(int)((t3 + 255) / 256), 256, 0, stream>>>(bufC, 28, 28, 256, chunk);
  }

  // text branch
  embed_mean_kernel<<<64, 256, 0, stream>>>(seq, len, emb, means);
  fc_kernel<512, 512, false><<<dim3(2, 32), 256, 0, stream>>>(
      means, 512, rnn_w, rnn_b, feats + 512, 1024);

  // image branch
  for (int n0 = 0; n0 < 64; n0 += chunk) {
    int nb = 64 - n0; if (nb > chunk) nb = chunk;
    conv1_s2<<<dim3(49, nb), 256, 0, stream>>>(
        images + (size_t)n0 * 3 * 224 * 224, cw1, cb1, bufA);
    conv3x3s2_mfma<64, 128, 56, 56><<<dim3(25 * nb, 1), 256, 0, stream>>>(
        bufA, pw2, cb2, bufB);
    conv3x3s2_mfma<128, 256, 28, 28><<<dim3(7 * nb, 2), 256, 0, stream>>>(
        bufB, pw3, cb3, bufC);
    conv3x3s2_mfma<256, 512, 14, 14><<<dim3(2 * nb, 4), 256, 0, stream>>>(
        bufC, pw4, cb4, bufD);
    avgpool_nhwc<<<nb, 256, 0, stream>>>(bufD, feats, n0);
  }

  // head
  fc_kernel<1024, 512, true ><<<dim3(2, 32), 256, 0, stream>>>(feats, 1024, fc1_w, fc1_b, h1, 512);
  fc_kernel<512,  512, true ><<<dim3(2, 32), 256, 0, stream>>>(h1,    512,  fc2_w, fc2_b, h2, 512);
  fc_kernel<512, 1000, false><<<dim3(4, 32), 256, 0, stream>>>(h2,    512,  clf_w, clf_b, out, 1000);
}

// Round 6
// 388.205 us; speedup vs baseline: 1.4039x; 1.1062x over previous
//
#include <hip/hip_runtime.h>
#include <hip/hip_bf16.h>
#include <cstddef>
#include <cstdint>

typedef unsigned short u16;
typedef __attribute__((ext_vector_type(8))) short bf16x8;   // 8 bf16 in 4 VGPRs
typedef __attribute__((ext_vector_type(4))) float f32x4;
typedef __attribute__((ext_vector_type(8))) unsigned short u16x8;

static __device__ __forceinline__ u16 f2bf(float x) {       // RNE f32->bf16
  unsigned u = __float_as_uint(x);
  u += 0x7fffu + ((u >> 16) & 1u);
  return (u16)(u >> 16);
}
static __device__ __forceinline__ float bflo(unsigned u) { return __uint_as_float(u << 16); }
static __device__ __forceinline__ float bfhi(unsigned u) { return __uint_as_float(u & 0xffff0000u); }

// async global->LDS, 16B/lane; LDS dest = wave-uniform base + lane*16 (m104)
static __device__ __forceinline__ void gll16(const u16* g, u16* l) {
  __builtin_amdgcn_global_load_lds(
      (const __attribute__((address_space(1))) void*)g,
      (__attribute__((address_space(3))) void*)l, 16, 0, 0);
}

// ---------------------------------------------------------------------------
// Zero the halos (row H, col W) of the three padded NHWC buffers - one launch.
// ---------------------------------------------------------------------------
static __device__ __forceinline__ void halo_store(u16* buf, int H, int W, int C,
                                                  long long i) {
  const int c8n = C >> 3;
  const int c8 = (int)(i % c8n);
  long long rem = i / c8n;
  const int p = (int)(rem % (W + 1 + H));
  const int n = (int)(rem / (W + 1 + H));
  int y, x;
  if (p <= W) { y = H; x = p; } else { y = p - (W + 1); x = W; }
  const u16x8 z = {0, 0, 0, 0, 0, 0, 0, 0};
  *(u16x8*)(buf + (((size_t)n * (H + 1) + y) * (W + 1) + x) * C + c8 * 8) = z;
}
__global__ __launch_bounds__(256) void zero_halo3(u16* __restrict__ A,
                                                  u16* __restrict__ B,
                                                  u16* __restrict__ Cb, int nimg) {
  long long i = (long long)blockIdx.x * 256 + threadIdx.x;
  const long long cA = (long long)nimg * 225 * 8;    // (112+113)*64/8
  const long long cB = (long long)nimg * 113 * 16;   // (56+57)*128/8
  const long long cC = (long long)nimg * 57 * 32;    // (28+29)*256/8
  if (i < cA) { halo_store(A, 112, 112, 64, i); return; }
  i -= cA;
  if (i < cB) { halo_store(B, 56, 56, 128, i); return; }
  i -= cB;
  if (i < cC) halo_store(Cb, 28, 28, 256, i);
}

// ---------------------------------------------------------------------------
// conv1: 3->64ch, 3x3 s2 SAME, fp32 NCHW in -> bf16 padded-NHWC out.
// Compute as before (27 taps x 64 outch per thread-pixel), but stores go
// through a 32KB LDS tile (XOR-swizzled 16B chunks) so global stores are
// lane-contiguous 16B (1KB/wave/instr, full cache lines) - fixes the 2.3x
// HBM write amplification of the direct 128B-stride stores.
// ---------------------------------------------------------------------------
__global__ __launch_bounds__(256) void conv1_s2(
    const float* __restrict__ in,   // [n][3][224][224]
    const float* __restrict__ w,    // [64][3][3][3] OIHW
    const float* __restrict__ bias,
    u16* __restrict__ out) {        // [n][113][113][64] (halo untouched)
  __shared__ float sw[64 * 27];
  __shared__ float sb[64];
  __shared__ u16 so[256 * 64];      // 32KB staging, 16B chunk = unit
  const int tid = threadIdx.x;
  if (tid < 64) sb[tid] = bias[tid];
  for (int i = tid; i < 64 * 27; i += 256) sw[i] = w[i];
  __syncthreads();
  const int n = blockIdx.y;
  const int by = blockIdx.x / 7, bx = blockIdx.x % 7;
  const int oy = by * 16 + (tid >> 4), ox = bx * 16 + (tid & 15);
  const float* ibase = in + (size_t)n * 3 * 224 * 224 + (size_t)(2 * oy) * 224 + 2 * ox;
  float v[27];
  #pragma unroll
  for (int c = 0; c < 3; ++c)
    #pragma unroll
    for (int r = 0; r < 3; ++r)
      #pragma unroll
      for (int s = 0; s < 3; ++s) {
        const int iy = 2 * oy + r, ix = 2 * ox + s;
        float x = 0.f;
        if (iy < 224 && ix < 224) x = ibase[(size_t)c * 224 * 224 + r * 224 + s];
        v[c * 9 + r * 3 + s] = x;
      }
  #pragma unroll
  for (int kc = 0; kc < 8; ++kc) {
    u16x8 pack;
    #pragma unroll
    for (int k8 = 0; k8 < 8; ++k8) {
      const int k = kc * 8 + k8;
      float a = sb[k];
      const float* wk = &sw[k * 27];
      #pragma unroll
      for (int t = 0; t < 27; ++t) a = fmaf(v[t], wk[t], a);
      pack[k8] = f2bf(fmaxf(a, 0.f));
    }
    *(u16x8*)&so[(tid * 8 + (kc ^ (tid & 7))) * 8] = pack;   // swizzled chunk
  }
  __syncthreads();
  // cooperative contiguous store of the 16x16x64-ch tile
  u16* obase = out + (((size_t)n * 113 + by * 16) * 113 + bx * 16) * 64;
  #pragma unroll
  for (int it = 0; it < 8; ++it) {
    const int row = it * 2 + (tid >> 7);       // 0..15
    const int q = tid & 127;                   // 16B chunk within 2KB row
    const int px = q >> 3, c8 = q & 7;
    const int p = row * 16 + px;
    u16x8 v8 = *(const u16x8*)&so[(p * 8 + (c8 ^ (p & 7))) * 8];
    *(u16x8*)(obase + ((size_t)row * 113 + px) * 64 + c8 * 8) = v8;
  }
}

// ---------------------------------------------------------------------------
// Weight repack (one launch for all three convs): OIHW fp32 -> fragment bf16.
// pw[((st)*NB + nfrag)*512 + lane*8 + j], st = tap*CB+cb
// ---------------------------------------------------------------------------
static __device__ __forceinline__ void pack_one(const float* __restrict__ w,
                                                u16* __restrict__ pw,
                                                int CB, int NB, int C, int idx) {
  const int j = idx & 7;
  const int L = (idx >> 3) & 63;
  int t = idx >> 9;
  const int nbg = t % NB; t /= NB;
  const int cb = t % CB;
  const int tap = t / CB;
  const int n = nbg * 16 + (L & 15);
  const int c = cb * 32 + ((L >> 4) << 3) + j;
  pw[idx] = f2bf(w[((size_t)n * C + c) * 9 + tap]);
}
__global__ __launch_bounds__(256) void pack_all(
    const float* __restrict__ w2, const float* __restrict__ w3,
    const float* __restrict__ w4, u16* __restrict__ p2,
    u16* __restrict__ p3, u16* __restrict__ p4) {
  int i = blockIdx.x * 256 + threadIdx.x;
  if (i < 9 * 64 * 128) { pack_one(w2, p2, 2, 8, 64, i); return; }
  i -= 9 * 64 * 128;
  if (i < 9 * 128 * 256) { pack_one(w3, p3, 4, 16, 128, i); return; }
  i -= 9 * 128 * 256;
  if (i < 9 * 256 * 512) pack_one(w4, p4, 8, 32, 256, i);
}

// ---------------------------------------------------------------------------
// Implicit-GEMM 3x3 s2 conv, m97-style LDS pipeline (unchanged from R5).
// ---------------------------------------------------------------------------
template<int C, int K, int OH, int OW>
__global__ __launch_bounds__(256) void conv3x3s2_mfma(
    const u16* __restrict__ in,   // [n][2OH+1][2OW+1][C] padded
    const u16* __restrict__ pw,   // packed fragment weights
    const float* __restrict__ bias,
    u16* __restrict__ out) {      // [n][OH+1][OW+1][K] padded
  constexpr int IH = 2 * OH, IW = 2 * OW;
  constexpr int PIW = IW + 1;
  constexpr int P = OH * OW;
  constexpr int BM = 128;
  constexpr int MB = (P + BM - 1) / BM;
  constexpr int CB = C / 32, NB = K / 16;
  constexpr int STEPS = 9 * CB;

  __shared__ u16 lds[2][8192];                // 2 x 16KB: A [0..4095], B [4096..]

  const int bm = blockIdx.x % MB;
  const int n = blockIdx.x / MB;
  const int nbh = blockIdx.y;                 // 128-outch group
  const int lane = threadIdx.x & 63, wv = threadIdx.x >> 6;
  const int mh = wv >> 1, nh = wv & 1;

  const u16* ibase = in + (size_t)n * ((IH + 1) * PIW * C);
  int s_abase[4];
  #pragma unroll
  for (int mf = 0; mf < 4; ++mf) {
    int pm = bm * BM + mh * 64 + mf * 16 + (lane & 15);
    int pc = pm < P ? pm : P - 1;             // clamp: dup loads, guarded store
    int oy = pc / OW, ox = pc % OW;
    s_abase[mf] = ((2 * oy) * PIW + 2 * ox) * C + ((lane >> 4) << 3);
  }

  f32x4 acc[4][4];
  #pragma unroll
  for (int mf = 0; mf < 4; ++mf)
    #pragma unroll
    for (int nf = 0; nf < 4; ++nf) acc[mf][nf] = (f32x4){0.f, 0.f, 0.f, 0.f};

  auto STAGE = [&](int st, int buf) {
    if (nh == 0) {                            // wv0/wv2: A for own mh
      const int cb = st & (CB - 1);
      const int tap = st / CB;                // CB is power of 2
      const int r = tap / 3, s = tap - 3 * r;
      const int toff = (r * PIW + s) * C + cb * 32;
      #pragma unroll
      for (int mf = 0; mf < 4; ++mf)
        gll16(ibase + s_abase[mf] + toff, &lds[buf][(mh * 4 + mf) * 512]);
    } else {                                  // wv1/wv3: B frags mh*4..mh*4+3
      const u16* bp = pw + ((size_t)st * NB + nbh * 8 + mh * 4) * 512 + lane * 8;
      #pragma unroll
      for (int nf = 0; nf < 4; ++nf)
        gll16(bp + nf * 512, &lds[buf][4096 + (mh * 4 + nf) * 512]);
    }
  };

  STAGE(0, 0);
  __syncthreads();
  for (int st = 0; st < STEPS; ++st) {
    const int buf = st & 1;
    if (st + 1 < STEPS) STAGE(st + 1, buf ^ 1);
    bf16x8 a[4], b[4];
    #pragma unroll
    for (int mf = 0; mf < 4; ++mf)
      a[mf] = *(const bf16x8*)&lds[buf][(mh * 4 + mf) * 512 + lane * 8];
    #pragma unroll
    for (int nf = 0; nf < 4; ++nf)
      b[nf] = *(const bf16x8*)&lds[buf][4096 + (nh * 4 + nf) * 512 + lane * 8];
    #pragma unroll
    for (int mf = 0; mf < 4; ++mf)
      #pragma unroll
      for (int nf = 0; nf < 4; ++nf)
        acc[mf][nf] = __builtin_amdgcn_mfma_f32_16x16x32_bf16(a[mf], b[nf], acc[mf][nf], 0, 0, 0);
    __syncthreads();
  }

  // Epilogue: D col=lane&15 (outch), row=(lane>>4)*4+reg (pixel)
  const int rowg = (lane >> 4) << 2;
  #pragma unroll
  for (int mf = 0; mf < 4; ++mf)
    #pragma unroll
    for (int nf = 0; nf < 4; ++nf) {
      const int ch = (nbh * 8 + nh * 4 + nf) * 16 + (lane & 15);
      const float bv = bias[ch];
      #pragma unroll
      for (int rr = 0; rr < 4; ++rr) {
        const int pix = bm * BM + mh * 64 + mf * 16 + rowg + rr;
        if (pix < P) {
          const int oy = pix / OW, ox = pix % OW;
          out[(((size_t)n * (OH + 1) + oy) * (OW + 1) + ox) * K + ch] =
              f2bf(fmaxf(acc[mf][nf][rr] + bv, 0.f));
        }
      }
    }
}

// ---------------------------------------------------------------------------
// Global avg pool over 14x14 of padded [nb][15][15][512] bf16 -> feats fp32.
// ---------------------------------------------------------------------------
__global__ __launch_bounds__(256) void avgpool_nhwc(
    const u16* __restrict__ in, float* __restrict__ feats, int n0) {
  const int n = blockIdx.x, t = threadIdx.x;
  const u16* p = in + (size_t)n * (15 * 15 * 512) + t * 2;
  float s0 = 0.f, s1 = 0.f;
  for (int y = 0; y < 14; ++y)
    #pragma unroll
    for (int x = 0; x < 14; ++x) {
      unsigned u = *(const unsigned*)(p + (size_t)(y * 15 + x) * 512);
      s0 += bflo(u);
      s1 += bfhi(u);
    }
  float* f = feats + (size_t)(n0 + n) * 1024;
  f[2 * t] = s0 * (1.f / 196.f);
  f[2 * t + 1] = s1 * (1.f / 196.f);
}

// ---------------------------------------------------------------------------
// Text branch: masked mean, 4 parallel s-chains (ILP) x 64 lanes x 8 dims.
// ---------------------------------------------------------------------------
__global__ __launch_bounds__(256) void embed_mean_kernel(
    const int* __restrict__ seq, const int* __restrict__ len,
    const float* __restrict__ emb, float* __restrict__ means) {
  __shared__ float part[3][512];
  const int b = blockIdx.x;
  const int L = len[b];
  const int sg = threadIdx.x >> 6;            // 0..3 s-chain
  const int d0 = (threadIdx.x & 63) * 8;      // 8 dims per lane
  float a[8] = {0.f, 0.f, 0.f, 0.f, 0.f, 0.f, 0.f, 0.f};
  for (int s = sg; s < L; s += 4) {
    const float* e = emb + (size_t)seq[b * 128 + s] * 512 + d0;
    float4 v0 = *(const float4*)e, v1 = *(const float4*)(e + 4);
    a[0] += v0.x; a[1] += v0.y; a[2] += v0.z; a[3] += v0.w;
    a[4] += v1.x; a[5] += v1.y; a[6] += v1.z; a[7] += v1.w;
  }
  if (sg) {
    #pragma unroll
    for (int j = 0; j < 8; ++j) part[sg - 1][d0 + j] = a[j];
  }
  __syncthreads();
  if (sg == 0) {
    const float inv = 1.f / (float)L;
    #pragma unroll
    for (int j = 0; j < 8; ++j)
      means[(size_t)b * 512 + d0 + j] =
          (a[j] + part[0][d0 + j] + part[1][d0 + j] + part[2][d0 + j]) * inv;
  }
}

// ---------------------------------------------------------------------------
// Small FC (fp32): 2 m-rows per block, 4-way k-ILP. W row-major [K][N].
// ---------------------------------------------------------------------------
template<int K, int N, bool RELU>
__global__ __launch_bounds__(256) void fc_kernel(
    const float* __restrict__ x, int ldx,
    const float* __restrict__ w, const float* __restrict__ bias,
    float* __restrict__ out, int ldo) {
  __shared__ float row[2][K];
  const int m0 = blockIdx.y * 2;
  for (int i = threadIdx.x; i < 2 * K; i += 256)
    row[i / K][i % K] = x[(size_t)(m0 + i / K) * ldx + (i % K)];
  __syncthreads();
  const int col = blockIdx.x * 256 + threadIdx.x;
  if (col < N) {
    float acc[2][4] = {{0.f, 0.f, 0.f, 0.f}, {0.f, 0.f, 0.f, 0.f}};
    for (int k = 0; k < K; k += 4) {
      float w0 = w[(size_t)(k + 0) * N + col];
      float w1 = w[(size_t)(k + 1) * N + col];
      float w2 = w[(size_t)(k + 2) * N + col];
      float w3 = w[(size_t)(k + 3) * N + col];
      #pragma unroll
      for (int m = 0; m < 2; ++m) {
        acc[m][0] = fmaf(row[m][k + 0], w0, acc[m][0]);
        acc[m][1] = fmaf(row[m][k + 1], w1, acc[m][1]);
        acc[m][2] = fmaf(row[m][k + 2], w2, acc[m][2]);
        acc[m][3] = fmaf(row[m][k + 3], w3, acc[m][3]);
      }
    }
    const float bv = bias[col];
    #pragma unroll
    for (int m = 0; m < 2; ++m) {
      float a = acc[m][0] + acc[m][1] + acc[m][2] + acc[m][3] + bv;
      out[(size_t)(m0 + m) * ldo + col] = RELU ? fmaxf(a, 0.f) : a;
    }
  }
}

// ---------------------------------------------------------------------------
extern "C" void kernel_launch(void* const* d_in, const int* in_sizes, int n_in,
                              void* d_out, int out_size, void* d_ws, size_t ws_size,
                              hipStream_t stream) {
  const float* images = (const float*)d_in[0];
  const int*   seq    = (const int*)d_in[1];
  const int*   len    = (const int*)d_in[2];
  const float* emb    = (const float*)d_in[4];
  const float* cw1 = (const float*)d_in[5];  const float* cb1 = (const float*)d_in[6];
  const float* cw2 = (const float*)d_in[7];  const float* cb2 = (const float*)d_in[8];
  const float* cw3 = (const float*)d_in[9];  const float* cb3 = (const float*)d_in[10];
  const float* cw4 = (const float*)d_in[11]; const float* cb4 = (const float*)d_in[12];
  const float* rnn_w = (const float*)d_in[13]; const float* rnn_b = (const float*)d_in[14];
  const float* fc1_w = (const float*)d_in[15]; const float* fc1_b = (const float*)d_in[16];
  const float* fc2_w = (const float*)d_in[17]; const float* fc2_b = (const float*)d_in[18];
  const float* clf_w = (const float*)d_in[19]; const float* clf_b = (const float*)d_in[20];
  float* out = (float*)d_out;

  // Padded NHWC buffers (elems/img)
  const size_t A_E = (size_t)113 * 113 * 64;   // conv1 out
  const size_t B_E = (size_t)57 * 57 * 128;    // conv2 out
  const size_t C_E = (size_t)29 * 29 * 256;    // conv3 out
  const size_t D_E = (size_t)15 * 15 * 512;    // conv4 out
  const size_t PW2_E = 9 * 64 * 128, PW3_E = 9 * 128 * 256, PW4_E = 9 * 256 * 512;
  const size_t PER_IMG = (A_E + B_E + C_E + D_E) * 2;
  const size_t FIXED = (PW2_E + PW3_E + PW4_E) * 2 +
                       (size_t)(64 * 512 + 64 * 1024 + 64 * 512 + 64 * 512) * 4;
  int chunk = 64;
  if (ws_size < FIXED + 64 * PER_IMG) {
    size_t avail = (ws_size > FIXED) ? (ws_size - FIXED) : 0;
    size_t c = avail / PER_IMG;
    chunk = (c < 1) ? 1 : (c > 64 ? 64 : (int)c);
  }
  u16* bufA = (u16*)d_ws;
  u16* bufB = bufA + (size_t)chunk * A_E;
  u16* bufC = bufB + (size_t)chunk * B_E;
  u16* bufD = bufC + (size_t)chunk * C_E;
  u16* pw2 = bufD + (size_t)chunk * D_E;
  u16* pw3 = pw2 + PW2_E;
  u16* pw4 = pw3 + PW3_E;
  float* means = (float*)(pw4 + PW4_E);
  float* feats = means + 64 * 512;
  float* h1 = feats + 64 * 1024;
  float* h2 = h1 + 64 * 512;

  // weight repack + halo zero (one launch each)
  {
    const int pk_total = 9 * 64 * 128 + 9 * 128 * 256 + 9 * 256 * 512;
    pack_all<<<(pk_total + 255) / 256, 256, 0, stream>>>(cw2, cw3, cw4, pw2, pw3, pw4);
    long long zt = (long long)chunk * (225 * 8 + 113 * 16 + 57 * 32);
    zero_halo3<<<(int)((zt + 255) / 256), 256, 0, stream>>>(bufA, bufB, bufC, chunk);
  }

  // text branch
  embed_mean_kernel<<<64, 256, 0, stream>>>(seq, len, emb, means);
  fc_kernel<512, 512, false><<<dim3(2, 32), 256, 0, stream>>>(
      means, 512, rnn_w, rnn_b, feats + 512, 1024);

  // image branch
  for (int n0 = 0; n0 < 64; n0 += chunk) {
    int nb = 64 - n0; if (nb > chunk) nb = chunk;
    conv1_s2<<<dim3(49, nb), 256, 0, stream>>>(
        images + (size_t)n0 * 3 * 224 * 224, cw1, cb1, bufA);
    conv3x3s2_mfma<64, 128, 56, 56><<<dim3(25 * nb, 1), 256, 0, stream>>>(
        bufA, pw2, cb2, bufB);
    conv3x3s2_mfma<128, 256, 28, 28><<<dim3(7 * nb, 2), 256, 0, stream>>>(
        bufB, pw3, cb3, bufC);
    conv3x3s2_mfma<256, 512, 14, 14><<<dim3(2 * nb, 4), 256, 0, stream>>>(
        bufC, pw4, cb4, bufD);
    avgpool_nhwc<<<nb, 256, 0, stream>>>(bufD, feats, n0);
  }

  // head
  fc_kernel<1024, 512, true ><<<dim3(2, 32), 256, 0, stream>>>(feats, 1024, fc1_w, fc1_b, h1, 512);
  fc_kernel<512,  512, true ><<<dim3(2, 32), 256, 0, stream>>>(h1,    512,  fc2_w, fc2_b, h2, 512);
  fc_kernel<512, 1000, false><<<dim3(4, 32), 256, 0, stream>>>(h2,    512,  clf_w, clf_b, out, 1000);
}

// Round 7
// 374.910 us; speedup vs baseline: 1.4537x; 1.0355x over previous
//
#include <hip/hip_runtime.h>
#include <hip/hip_bf16.h>
#include <cstddef>
#include <cstdint>

typedef unsigned short u16;
typedef __attribute__((ext_vector_type(8))) short bf16x8;   // 8 bf16 in 4 VGPRs
typedef __attribute__((ext_vector_type(4))) float f32x4;
typedef __attribute__((ext_vector_type(8))) unsigned short u16x8;

static __device__ __forceinline__ u16 f2bf(float x) {       // RNE f32->bf16
  unsigned u = __float_as_uint(x);
  u += 0x7fffu + ((u >> 16) & 1u);
  return (u16)(u >> 16);
}
static __device__ __forceinline__ float bflo(unsigned u) { return __uint_as_float(u << 16); }
static __device__ __forceinline__ float bfhi(unsigned u) { return __uint_as_float(u & 0xffff0000u); }

// async global->LDS, 16B/lane; LDS dest = wave-uniform base + lane*16 (m104)
static __device__ __forceinline__ void gll16(const u16* g, u16* l) {
  __builtin_amdgcn_global_load_lds(
      (const __attribute__((address_space(1))) void*)g,
      (__attribute__((address_space(3))) void*)l, 16, 0, 0);
}

// ---------------------------------------------------------------------------
// Zero the halos (row H, col W) of the three padded NHWC buffers - one launch.
// ---------------------------------------------------------------------------
static __device__ __forceinline__ void halo_store(u16* buf, int H, int W, int C,
                                                  long long i) {
  const int c8n = C >> 3;
  const int c8 = (int)(i % c8n);
  long long rem = i / c8n;
  const int p = (int)(rem % (W + 1 + H));
  const int n = (int)(rem / (W + 1 + H));
  int y, x;
  if (p <= W) { y = H; x = p; } else { y = p - (W + 1); x = W; }
  const u16x8 z = {0, 0, 0, 0, 0, 0, 0, 0};
  *(u16x8*)(buf + (((size_t)n * (H + 1) + y) * (W + 1) + x) * C + c8 * 8) = z;
}
__global__ __launch_bounds__(256) void zero_halo3(u16* __restrict__ A,
                                                  u16* __restrict__ B,
                                                  u16* __restrict__ Cb, int nimg) {
  long long i = (long long)blockIdx.x * 256 + threadIdx.x;
  const long long cA = (long long)nimg * 225 * 8;    // (112+113)*64/8
  const long long cB = (long long)nimg * 113 * 16;   // (56+57)*128/8
  const long long cC = (long long)nimg * 57 * 32;    // (28+29)*256/8
  if (i < cA) { halo_store(A, 112, 112, 64, i); return; }
  i -= cA;
  if (i < cB) { halo_store(B, 56, 56, 128, i); return; }
  i -= cB;
  if (i < cC) halo_store(Cb, 28, 28, 256, i);
}

// ---------------------------------------------------------------------------
// conv1: 3->64ch, 3x3 s2 SAME, fp32 NCHW in -> bf16 padded-NHWC out.
// LDS-staged transposed stores (full-line 16B/lane bursts).
// ---------------------------------------------------------------------------
__global__ __launch_bounds__(256) void conv1_s2(
    const float* __restrict__ in,   // [n][3][224][224]
    const float* __restrict__ w,    // [64][3][3][3] OIHW
    const float* __restrict__ bias,
    u16* __restrict__ out) {        // [n][113][113][64] (halo untouched)
  __shared__ float sw[64 * 27];
  __shared__ float sb[64];
  __shared__ u16 so[256 * 64];      // 32KB staging, 16B chunk = unit
  const int tid = threadIdx.x;
  if (tid < 64) sb[tid] = bias[tid];
  for (int i = tid; i < 64 * 27; i += 256) sw[i] = w[i];
  __syncthreads();
  const int n = blockIdx.y;
  const int by = blockIdx.x / 7, bx = blockIdx.x % 7;
  const int oy = by * 16 + (tid >> 4), ox = bx * 16 + (tid & 15);
  const float* ibase = in + (size_t)n * 3 * 224 * 224 + (size_t)(2 * oy) * 224 + 2 * ox;
  float v[27];
  #pragma unroll
  for (int c = 0; c < 3; ++c)
    #pragma unroll
    for (int r = 0; r < 3; ++r)
      #pragma unroll
      for (int s = 0; s < 3; ++s) {
        const int iy = 2 * oy + r, ix = 2 * ox + s;
        float x = 0.f;
        if (iy < 224 && ix < 224) x = ibase[(size_t)c * 224 * 224 + r * 224 + s];
        v[c * 9 + r * 3 + s] = x;
      }
  #pragma unroll
  for (int kc = 0; kc < 8; ++kc) {
    u16x8 pack;
    #pragma unroll
    for (int k8 = 0; k8 < 8; ++k8) {
      const int k = kc * 8 + k8;
      float a = sb[k];
      const float* wk = &sw[k * 27];
      #pragma unroll
      for (int t = 0; t < 27; ++t) a = fmaf(v[t], wk[t], a);
      pack[k8] = f2bf(fmaxf(a, 0.f));
    }
    *(u16x8*)&so[(tid * 8 + (kc ^ (tid & 7))) * 8] = pack;   // swizzled chunk
  }
  __syncthreads();
  // cooperative contiguous store of the 16x16x64-ch tile
  u16* obase = out + (((size_t)n * 113 + by * 16) * 113 + bx * 16) * 64;
  #pragma unroll
  for (int it = 0; it < 8; ++it) {
    const int row = it * 2 + (tid >> 7);       // 0..15
    const int q = tid & 127;                   // 16B chunk within 2KB row
    const int px = q >> 3, c8 = q & 7;
    const int p = row * 16 + px;
    u16x8 v8 = *(const u16x8*)&so[(p * 8 + (c8 ^ (p & 7))) * 8];
    *(u16x8*)(obase + ((size_t)row * 113 + px) * 64 + c8 * 8) = v8;
  }
}

// ---------------------------------------------------------------------------
// Weight repack (one launch): OIHW fp32 -> fragment bf16.
// ---------------------------------------------------------------------------
static __device__ __forceinline__ void pack_one(const float* __restrict__ w,
                                                u16* __restrict__ pw,
                                                int CB, int NB, int C, int idx) {
  const int j = idx & 7;
  const int L = (idx >> 3) & 63;
  int t = idx >> 9;
  const int nbg = t % NB; t /= NB;
  const int cb = t % CB;
  const int tap = t / CB;
  const int n = nbg * 16 + (L & 15);
  const int c = cb * 32 + ((L >> 4) << 3) + j;
  pw[idx] = f2bf(w[((size_t)n * C + c) * 9 + tap]);
}
__global__ __launch_bounds__(256) void pack_all(
    const float* __restrict__ w2, const float* __restrict__ w3,
    const float* __restrict__ w4, u16* __restrict__ p2,
    u16* __restrict__ p3, u16* __restrict__ p4) {
  int i = blockIdx.x * 256 + threadIdx.x;
  if (i < 9 * 64 * 128) { pack_one(w2, p2, 2, 8, 64, i); return; }
  i -= 9 * 64 * 128;
  if (i < 9 * 128 * 256) { pack_one(w3, p3, 4, 16, 128, i); return; }
  i -= 9 * 128 * 256;
  if (i < 9 * 256 * 512) pack_one(w4, p4, 8, 32, 256, i);
}

// ---------------------------------------------------------------------------
// Implicit-GEMM 3x3 s2 conv: 3-buffer LDS pipeline, prefetch depth 2,
// COUNTED vmcnt (T3/T4): per phase computing step s, issue step s+2's 4
// global_load_lds per wave, ds_read+16 MFMA on buf[s%3], then
// s_waitcnt vmcnt(4) (waits only s+1's batch; s+2 stays in flight) +
// raw s_barrier + sched_barrier(0). Never drains to 0 in the main loop.
// ---------------------------------------------------------------------------
template<int C, int K, int OH, int OW>
__global__ __launch_bounds__(256, 3) void conv3x3s2_mfma(
    const u16* __restrict__ in,   // [n][2OH+1][2OW+1][C] padded
    const u16* __restrict__ pw,   // packed fragment weights
    const float* __restrict__ bias,
    u16* __restrict__ out) {      // [n][OH+1][OW+1][K] padded
  constexpr int IH = 2 * OH, IW = 2 * OW;
  constexpr int PIW = IW + 1;
  constexpr int P = OH * OW;
  constexpr int BM = 128;
  constexpr int MB = (P + BM - 1) / BM;
  constexpr int CB = C / 32, NB = K / 16;
  constexpr int STEPS = 9 * CB;               // 18 / 36 / 72 : all % 3 == 0
  static_assert(STEPS % 3 == 0, "triple-buffer rotation needs STEPS%3==0");

  __shared__ u16 lds[3][8192];                // 3 x 16KB: A [0..4095], B [4096..]

  const int bm = blockIdx.x % MB;
  const int n = blockIdx.x / MB;
  const int nbh = blockIdx.y;                 // 128-outch group
  const int lane = threadIdx.x & 63, wv = threadIdx.x >> 6;
  const int mh = wv >> 1, nh = wv & 1;

  const u16* ibase = in + (size_t)n * ((IH + 1) * PIW * C);
  int s_abase[4];
  #pragma unroll
  for (int mf = 0; mf < 4; ++mf) {
    int pm = bm * BM + mh * 64 + mf * 16 + (lane & 15);
    int pc = pm < P ? pm : P - 1;             // clamp: dup loads, guarded store
    int oy = pc / OW, ox = pc % OW;
    s_abase[mf] = ((2 * oy) * PIW + 2 * ox) * C + ((lane >> 4) << 3);
  }

  f32x4 acc[4][4];
  #pragma unroll
  for (int mf = 0; mf < 4; ++mf)
    #pragma unroll
    for (int nf = 0; nf < 4; ++nf) acc[mf][nf] = (f32x4){0.f, 0.f, 0.f, 0.f};

  auto STAGE = [&](int st, int buf) {         // 4 gll16 per wave
    if (nh == 0) {                            // wv0/wv2: A for own mh
      const int cb = st & (CB - 1);
      const int tap = st / CB;                // CB is power of 2
      const int r = tap / 3, s = tap - 3 * r;
      const int toff = (r * PIW + s) * C + cb * 32;
      #pragma unroll
      for (int mf = 0; mf < 4; ++mf)
        gll16(ibase + s_abase[mf] + toff, &lds[buf][(mh * 4 + mf) * 512]);
    } else {                                  // wv1/wv3: B frags mh*4..mh*4+3
      const u16* bp = pw + ((size_t)st * NB + nbh * 8 + mh * 4) * 512 + lane * 8;
      #pragma unroll
      for (int nf = 0; nf < 4; ++nf)
        gll16(bp + nf * 512, &lds[buf][4096 + (mh * 4 + nf) * 512]);
    }
  };
  auto COMPUTE = [&](int buf) {
    bf16x8 a[4], b[4];
    #pragma unroll
    for (int mf = 0; mf < 4; ++mf)
      a[mf] = *(const bf16x8*)&lds[buf][(mh * 4 + mf) * 512 + lane * 8];
    #pragma unroll
    for (int nf = 0; nf < 4; ++nf)
      b[nf] = *(const bf16x8*)&lds[buf][4096 + (nh * 4 + nf) * 512 + lane * 8];
    #pragma unroll
    for (int mf = 0; mf < 4; ++mf)
      #pragma unroll
      for (int nf = 0; nf < 4; ++nf)
        acc[mf][nf] = __builtin_amdgcn_mfma_f32_16x16x32_bf16(a[mf], b[nf], acc[mf][nf], 0, 0, 0);
  };
  // phase computing step s, staging s+2 into bufS (= s+2 mod 3)
  auto PHASE = [&](int s, int bufC, int bufS) {
    const bool more = (s + 2) < STEPS;
    if (more) STAGE(s + 2, bufS);
    COMPUTE(bufC);
    if (more) asm volatile("s_waitcnt vmcnt(4)" ::: "memory");
    else      asm volatile("s_waitcnt vmcnt(0)" ::: "memory");
    __builtin_amdgcn_s_barrier();
    __builtin_amdgcn_sched_barrier(0);
  };

  STAGE(0, 0);
  STAGE(1, 1);
  asm volatile("s_waitcnt vmcnt(4)" ::: "memory");   // step-0 batch landed
  __builtin_amdgcn_s_barrier();
  __builtin_amdgcn_sched_barrier(0);

  for (int st = 0; st < STEPS; st += 3) {
    PHASE(st + 0, 0, 2);
    PHASE(st + 1, 1, 0);
    PHASE(st + 2, 2, 1);
  }

  // Epilogue: D col=lane&15 (outch), row=(lane>>4)*4+reg (pixel)
  const int rowg = (lane >> 4) << 2;
  #pragma unroll
  for (int mf = 0; mf < 4; ++mf)
    #pragma unroll
    for (int nf = 0; nf < 4; ++nf) {
      const int ch = (nbh * 8 + nh * 4 + nf) * 16 + (lane & 15);
      const float bv = bias[ch];
      #pragma unroll
      for (int rr = 0; rr < 4; ++rr) {
        const int pix = bm * BM + mh * 64 + mf * 16 + rowg + rr;
        if (pix < P) {
          const int oy = pix / OW, ox = pix % OW;
          out[(((size_t)n * (OH + 1) + oy) * (OW + 1) + ox) * K + ch] =
              f2bf(fmaxf(acc[mf][nf][rr] + bv, 0.f));
        }
      }
    }
}

// ---------------------------------------------------------------------------
// Global avg pool over 14x14 of padded [nb][15][15][512] bf16 -> feats fp32.
// ---------------------------------------------------------------------------
__global__ __launch_bounds__(256) void avgpool_nhwc(
    const u16* __restrict__ in, float* __restrict__ feats, int n0) {
  const int n = blockIdx.x, t = threadIdx.x;
  const u16* p = in + (size_t)n * (15 * 15 * 512) + t * 2;
  float s0 = 0.f, s1 = 0.f;
  for (int y = 0; y < 14; ++y)
    #pragma unroll
    for (int x = 0; x < 14; ++x) {
      unsigned u = *(const unsigned*)(p + (size_t)(y * 15 + x) * 512);
      s0 += bflo(u);
      s1 += bfhi(u);
    }
  float* f = feats + (size_t)(n0 + n) * 1024;
  f[2 * t] = s0 * (1.f / 196.f);
  f[2 * t + 1] = s1 * (1.f / 196.f);
}

// ---------------------------------------------------------------------------
// Text branch: masked mean, 4 parallel s-chains (ILP) x 64 lanes x 8 dims.
// ---------------------------------------------------------------------------
__global__ __launch_bounds__(256) void embed_mean_kernel(
    const int* __restrict__ seq, const int* __restrict__ len,
    const float* __restrict__ emb, float* __restrict__ means) {
  __shared__ float part[3][512];
  const int b = blockIdx.x;
  const int L = len[b];
  const int sg = threadIdx.x >> 6;            // 0..3 s-chain
  const int d0 = (threadIdx.x & 63) * 8;      // 8 dims per lane
  float a[8] = {0.f, 0.f, 0.f, 0.f, 0.f, 0.f, 0.f, 0.f};
  for (int s = sg; s < L; s += 4) {
    const float* e = emb + (size_t)seq[b * 128 + s] * 512 + d0;
    float4 v0 = *(const float4*)e, v1 = *(const float4*)(e + 4);
    a[0] += v0.x; a[1] += v0.y; a[2] += v0.z; a[3] += v0.w;
    a[4] += v1.x; a[5] += v1.y; a[6] += v1.z; a[7] += v1.w;
  }
  if (sg) {
    #pragma unroll
    for (int j = 0; j < 8; ++j) part[sg - 1][d0 + j] = a[j];
  }
  __syncthreads();
  if (sg == 0) {
    const float inv = 1.f / (float)L;
    #pragma unroll
    for (int j = 0; j < 8; ++j)
      means[(size_t)b * 512 + d0 + j] =
          (a[j] + part[0][d0 + j] + part[1][d0 + j] + part[2][d0 + j]) * inv;
  }
}

// ---------------------------------------------------------------------------
// Small FC (fp32): 2 m-rows per block, 4-way k-ILP. W row-major [K][N].
// ---------------------------------------------------------------------------
template<int K, int N, bool RELU>
__global__ __launch_bounds__(256) void fc_kernel(
    const float* __restrict__ x, int ldx,
    const float* __restrict__ w, const float* __restrict__ bias,
    float* __restrict__ out, int ldo) {
  __shared__ float row[2][K];
  const int m0 = blockIdx.y * 2;
  for (int i = threadIdx.x; i < 2 * K; i += 256)
    row[i / K][i % K] = x[(size_t)(m0 + i / K) * ldx + (i % K)];
  __syncthreads();
  const int col = blockIdx.x * 256 + threadIdx.x;
  if (col < N) {
    float acc[2][4] = {{0.f, 0.f, 0.f, 0.f}, {0.f, 0.f, 0.f, 0.f}};
    for (int k = 0; k < K; k += 4) {
      float w0 = w[(size_t)(k + 0) * N + col];
      float w1 = w[(size_t)(k + 1) * N + col];
      float w2 = w[(size_t)(k + 2) * N + col];
      float w3 = w[(size_t)(k + 3) * N + col];
      #pragma unroll
      for (int m = 0; m < 2; ++m) {
        acc[m][0] = fmaf(row[m][k + 0], w0, acc[m][0]);
        acc[m][1] = fmaf(row[m][k + 1], w1, acc[m][1]);
        acc[m][2] = fmaf(row[m][k + 2], w2, acc[m][2]);
        acc[m][3] = fmaf(row[m][k + 3], w3, acc[m][3]);
      }
    }
    const float bv = bias[col];
    #pragma unroll
    for (int m = 0; m < 2; ++m) {
      float a = acc[m][0] + acc[m][1] + acc[m][2] + acc[m][3] + bv;
      out[(size_t)(m0 + m) * ldo + col] = RELU ? fmaxf(a, 0.f) : a;
    }
  }
}

// ---------------------------------------------------------------------------
extern "C" void kernel_launch(void* const* d_in, const int* in_sizes, int n_in,
                              void* d_out, int out_size, void* d_ws, size_t ws_size,
                              hipStream_t stream) {
  const float* images = (const float*)d_in[0];
  const int*   seq    = (const int*)d_in[1];
  const int*   len    = (const int*)d_in[2];
  const float* emb    = (const float*)d_in[4];
  const float* cw1 = (const float*)d_in[5];  const float* cb1 = (const float*)d_in[6];
  const float* cw2 = (const float*)d_in[7];  const float* cb2 = (const float*)d_in[8];
  const float* cw3 = (const float*)d_in[9];  const float* cb3 = (const float*)d_in[10];
  const float* cw4 = (const float*)d_in[11]; const float* cb4 = (const float*)d_in[12];
  const float* rnn_w = (const float*)d_in[13]; const float* rnn_b = (const float*)d_in[14];
  const float* fc1_w = (const float*)d_in[15]; const float* fc1_b = (const float*)d_in[16];
  const float* fc2_w = (const float*)d_in[17]; const float* fc2_b = (const float*)d_in[18];
  const float* clf_w = (const float*)d_in[19]; const float* clf_b = (const float*)d_in[20];
  float* out = (float*)d_out;

  // Padded NHWC buffers (elems/img)
  const size_t A_E = (size_t)113 * 113 * 64;   // conv1 out
  const size_t B_E = (size_t)57 * 57 * 128;    // conv2 out
  const size_t C_E = (size_t)29 * 29 * 256;    // conv3 out
  const size_t D_E = (size_t)15 * 15 * 512;    // conv4 out
  const size_t PW2_E = 9 * 64 * 128, PW3_E = 9 * 128 * 256, PW4_E = 9 * 256 * 512;
  const size_t PER_IMG = (A_E + B_E + C_E + D_E) * 2;
  const size_t FIXED = (PW2_E + PW3_E + PW4_E) * 2 +
                       (size_t)(64 * 512 + 64 * 1024 + 64 * 512 + 64 * 512) * 4;
  int chunk = 64;
  if (ws_size < FIXED + 64 * PER_IMG) {
    size_t avail = (ws_size > FIXED) ? (ws_size - FIXED) : 0;
    size_t c = avail / PER_IMG;
    chunk = (c < 1) ? 1 : (c > 64 ? 64 : (int)c);
  }
  u16* bufA = (u16*)d_ws;
  u16* bufB = bufA + (size_t)chunk * A_E;
  u16* bufC = bufB + (size_t)chunk * B_E;
  u16* bufD = bufC + (size_t)chunk * C_E;
  u16* pw2 = bufD + (size_t)chunk * D_E;
  u16* pw3 = pw2 + PW2_E;
  u16* pw4 = pw3 + PW3_E;
  float* means = (float*)(pw4 + PW4_E);
  float* feats = means + 64 * 512;
  float* h1 = feats + 64 * 1024;
  float* h2 = h1 + 64 * 512;

  // weight repack + halo zero (one launch each)
  {
    const int pk_total = 9 * 64 * 128 + 9 * 128 * 256 + 9 * 256 * 512;
    pack_all<<<(pk_total + 255) / 256, 256, 0, stream>>>(cw2, cw3, cw4, pw2, pw3, pw4);
    long long zt = (long long)chunk * (225 * 8 + 113 * 16 + 57 * 32);
    zero_halo3<<<(int)((zt + 255) / 256), 256, 0, stream>>>(bufA, bufB, bufC, chunk);
  }

  // text branch
  embed_mean_kernel<<<64, 256, 0, stream>>>(seq, len, emb, means);
  fc_kernel<512, 512, false><<<dim3(2, 32), 256, 0, stream>>>(
      means, 512, rnn_w, rnn_b, feats + 512, 1024);

  // image branch
  for (int n0 = 0; n0 < 64; n0 += chunk) {
    int nb = 64 - n0; if (nb > chunk) nb = chunk;
    conv1_s2<<<dim3(49, nb), 256, 0, stream>>>(
        images + (size_t)n0 * 3 * 224 * 224, cw1, cb1, bufA);
    conv3x3s2_mfma<64, 128, 56, 56><<<dim3(25 * nb, 1), 256, 0, stream>>>(
        bufA, pw2, cb2, bufB);
    conv3x3s2_mfma<128, 256, 28, 28><<<dim3(7 * nb, 2), 256, 0, stream>>>(
        bufB, pw3, cb3, bufC);
    conv3x3s2_mfma<256, 512, 14, 14><<<dim3(2 * nb, 4), 256, 0, stream>>>(
        bufC, pw4, cb4, bufD);
    avgpool_nhwc<<<nb, 256, 0, stream>>>(bufD, feats, n0);
  }

  // head
  fc_kernel<1024, 512, true ><<<dim3(2, 32), 256, 0, stream>>>(feats, 1024, fc1_w, fc1_b, h1, 512);
  fc_kernel<512,  512, true ><<<dim3(2, 32), 256, 0, stream>>>(h1,    512,  fc2_w, fc2_b, h2, 512);
  fc_kernel<512, 1000, false><<<dim3(4, 32), 256, 0, stream>>>(h2,    512,  clf_w, clf_b, out, 1000);
}